// Round 1
// baseline (584.777 us; speedup 1.0000x reference)
//
#include <hip/hip_runtime.h>
#include <hip/hip_bf16.h>

typedef __attribute__((ext_vector_type(8))) short bf16x8;
typedef __attribute__((ext_vector_type(4))) float f32x4;

__device__ __forceinline__ unsigned short f2bf(float f){
  __hip_bfloat16 h = __float2bfloat16(f);
  return *reinterpret_cast<unsigned short*>(&h);
}

#define GLDS16(gptr, lptr) \
  __builtin_amdgcn_global_load_lds((const __attribute__((address_space(1))) unsigned int*)(gptr), \
                                   (__attribute__((address_space(3))) unsigned int*)(lptr), 16, 0, 0)

// ---------------- small prep kernels ----------------
__global__ void cvtk(const float* __restrict__ s, unsigned short* __restrict__ d, int n){
  int i = blockIdx.x*256 + threadIdx.x;
  if (i < n) d[i] = f2bf(s[i]);
}

__global__ void biask(const int* __restrict__ ri, const float* __restrict__ tbl, float* __restrict__ out){
  int g = blockIdx.x*256 + threadIdx.x;
  if (g < 8*9604){
    int h = g / 9604, ij = g % 9604;
    out[g] = tbl[ri[ij]*8 + h];
  }
}

// ---------------- LayerNorm (+optional shift/window map) ----------------
// mode 0: read x at shifted/natural coords, write windowed order (for attention path)
// mode 1: identity token map (LN2)
__launch_bounds__(256)
__global__ void lnk(const float* __restrict__ xin, const float* __restrict__ gw, const float* __restrict__ gb,
                    unsigned short* __restrict__ hout, int mode)
{
  int wid = threadIdx.x >> 6, lane = threadIdx.x & 63;
  int tok = blockIdx.x*4 + wid;
  int src;
  if (mode == 0){
    int w = tok / 98, n = tok % 98;
    int b = w >> 9, rr = w & 511;
    int di = rr >> 6, hi = (rr >> 3) & 7, wi = rr & 7;
    int d2 = n / 49, n2 = n % 49, h2 = n2 / 7, w2 = n2 % 7;
    int sd = (di*2 + d2 + 1) & 15;
    int sh = hi*7 + h2 + 3; if (sh >= 56) sh -= 56;
    int sw = wi*7 + w2 + 3; if (sw >= 56) sw -= 56;
    src = ((b*16 + sd)*56 + sh)*56 + sw;
  } else {
    src = tok;
  }
  float4 v = *(const float4*)(xin + (size_t)src*256 + lane*4);
  float s  = v.x + v.y + v.z + v.w;
  float s2 = v.x*v.x + v.y*v.y + v.z*v.z + v.w*v.w;
  #pragma unroll
  for (int off = 1; off < 64; off <<= 1){
    s  += __shfl_xor(s, off);
    s2 += __shfl_xor(s2, off);
  }
  float mean = s * (1.f/256.f);
  float var  = s2 * (1.f/256.f) - mean*mean;
  float rstd = rsqrtf(var + 1e-5f);
  int c = lane*4;
  float4 wv = *(const float4*)(gw + c);
  float4 bv = *(const float4*)(gb + c);
  unsigned int p0 = (unsigned int)f2bf((v.x-mean)*rstd*wv.x + bv.x)
                  | ((unsigned int)f2bf((v.y-mean)*rstd*wv.y + bv.y) << 16);
  unsigned int p1 = (unsigned int)f2bf((v.z-mean)*rstd*wv.z + bv.z)
                  | ((unsigned int)f2bf((v.w-mean)*rstd*wv.w + bv.w) << 16);
  uint2 pk; pk.x = p0; pk.y = p1;
  *(uint2*)(hout + (size_t)tok*256 + c) = pk;
}

// ---------------- bf16 MFMA GEMM: C[M,N] = A[M,K] * Bw[N,K]^T + bias ----------------
// 128x128 tile, 4 waves (2x2), BK=32, global_load_lds width-16 staging.
// EPI 0: qkv scatter (+q scale)   EPI 1: proj + unwindow/unroll + residual
// EPI 2: fc1 + GELU(erf) -> bf16  EPI 3: fc2 accumulate into d_out
template<int EPI>
__launch_bounds__(256, 2)
__global__ void gemmk(const unsigned short* __restrict__ A, const unsigned short* __restrict__ Bw,
                      const float* __restrict__ bias, int K, int nbx,
                      unsigned short* __restrict__ outb, const float* __restrict__ xres,
                      float* __restrict__ outf, int moff)
{
  __shared__ unsigned short As[128*32];
  __shared__ unsigned short Bs[128*32];
  int tid = threadIdx.x;
  int wid = tid >> 6, lane = tid & 63, l16 = lane & 15, lk = lane >> 4;
  int wm = wid >> 1, wn = wid & 1;
  int mblk = blockIdx.x / nbx, nblk = blockIdx.x % nbx;
  const unsigned short* Ab = A  + (size_t)mblk*128*K;
  const unsigned short* Bb = Bw + (size_t)nblk*128*K;
  int rA = tid >> 2, kcA = (tid & 3)*8;

  f32x4 acc[4][4];
  #pragma unroll
  for (int i = 0; i < 4; i++)
    #pragma unroll
    for (int j = 0; j < 4; j++)
      acc[i][j] = (f32x4){0.f,0.f,0.f,0.f};

  for (int ks = 0; ks < K; ks += 32){
    __syncthreads();
    GLDS16(Ab + (size_t)rA*K      + ks + kcA, &As[wid*512]);
    GLDS16(Ab + (size_t)(rA+64)*K + ks + kcA, &As[2048 + wid*512]);
    GLDS16(Bb + (size_t)rA*K      + ks + kcA, &Bs[wid*512]);
    GLDS16(Bb + (size_t)(rA+64)*K + ks + kcA, &Bs[2048 + wid*512]);
    __syncthreads();
    bf16x8 af[4], bfr[4];
    #pragma unroll
    for (int mi = 0; mi < 4; mi++) af[mi]  = *(const bf16x8*)&As[(wm*64 + mi*16 + l16)*32 + lk*8];
    #pragma unroll
    for (int ni = 0; ni < 4; ni++) bfr[ni] = *(const bf16x8*)&Bs[(wn*64 + ni*16 + l16)*32 + lk*8];
    #pragma unroll
    for (int mi = 0; mi < 4; mi++)
      #pragma unroll
      for (int ni = 0; ni < 4; ni++)
        acc[mi][ni] = __builtin_amdgcn_mfma_f32_16x16x32_bf16(af[mi], bfr[ni], acc[mi][ni], 0, 0, 0);
  }

  int rowb = mblk*128 + wm*64;
  int colb = nblk*128 + wn*64;
  #pragma unroll
  for (int mi = 0; mi < 4; mi++){
    #pragma unroll
    for (int r = 0; r < 4; r++){
      int row = rowb + mi*16 + lk*4 + r;
      if constexpr (EPI == 0){
        int w = row / 98, n = row % 98;
        size_t obase = ((size_t)w*8)*3136 + (size_t)n*32;
        #pragma unroll
        for (int ni = 0; ni < 4; ni++){
          int col = colb + ni*16 + l16;
          float v = acc[mi][ni][r] + bias[col];
          int which = col >> 8, head = (col >> 5) & 7, e = col & 31;
          if (which == 0) v *= 0.17677669529663687f;
          outb[(size_t)which*25690112 + obase + (size_t)head*3136 + e] = f2bf(v);
        }
      } else if constexpr (EPI == 1){
        int w = row / 98, n = row % 98;
        int b = w >> 9, rr = w & 511;
        int di = rr >> 6, hi = (rr >> 3) & 7, wi = rr & 7;
        int d2 = n / 49, n2 = n % 49, h2 = n2 / 7, w2 = n2 % 7;
        int sd = (di*2 + d2 + 1) & 15;
        int sh = hi*7 + h2 + 3; if (sh >= 56) sh -= 56;
        int sw = wi*7 + w2 + 3; if (sw >= 56) sw -= 56;
        size_t tnat = (((size_t)b*16 + sd)*56 + sh)*56 + sw;
        #pragma unroll
        for (int ni = 0; ni < 4; ni++){
          int col = colb + ni*16 + l16;
          float v = acc[mi][ni][r] + bias[col];
          outf[tnat*256 + col] = xres[tnat*256 + col] + v;
        }
      } else if constexpr (EPI == 2){
        #pragma unroll
        for (int ni = 0; ni < 4; ni++){
          int col = colb + ni*16 + l16;
          float v = acc[mi][ni][r] + bias[col];
          float gl = v * 0.5f * (1.f + erff(v * 0.70710678118654752f));
          outb[(size_t)row*1024 + col] = f2bf(gl);
        }
      } else {
        #pragma unroll
        for (int ni = 0; ni < 4; ni++){
          int col = colb + ni*16 + l16;
          float v = acc[mi][ni][r] + bias[col];
          outf[((size_t)(moff + row))*256 + col] += v;
        }
      }
    }
  }
}

// ---------------- fused window attention ----------------
// one wave per (window, head, m-tile of 16 q-rows); 7 QK^T MFMA + softmax + 8 PV MFMA
__launch_bounds__(256, 2)
__global__ void attnk(const unsigned short* __restrict__ qkv, const float* __restrict__ biasf,
                      const float* __restrict__ mask, unsigned short* __restrict__ obuf)
{
  __shared__ unsigned short P[4][16*136];   // stride 136 breaks the 256B-stride bank conflict
  int tid = threadIdx.x, wid = tid >> 6, lane = tid & 63, l16 = lane & 15, lk = lane >> 4;
  int task = blockIdx.x*4 + wid;            // 14336*4 = 57344 = 1024*8*7
  int mt = task % 7, wh = task / 7;
  int w = wh >> 3, h = wh & 7;
  const unsigned short* qb = qkv + ((size_t)w*8 + h)*3136;
  const unsigned short* kb = qb + 25690112;
  const unsigned short* vb = kb + 25690112;

  int qrow = mt*16 + l16; if (qrow > 97) qrow = 97;
  bf16x8 qa = *(const bf16x8*)(qb + qrow*32 + lk*8);

  f32x4 s[7];
  #pragma unroll
  for (int nt = 0; nt < 7; nt++){
    int kc = nt*16 + l16; if (kc > 97) kc = 97;
    bf16x8 kf = *(const bf16x8*)(kb + kc*32 + lk*8);
    f32x4 z = (f32x4){0.f,0.f,0.f,0.f};
    s[nt] = __builtin_amdgcn_mfma_f32_16x16x32_bf16(qa, kf, z, 0, 0, 0);
  }

  const float* bh = biasf + h*9604;
  const float* mm = mask + (size_t)(w & 511)*9604;
  float mx[4] = {-3e38f,-3e38f,-3e38f,-3e38f};
  #pragma unroll
  for (int r = 0; r < 4; r++){
    int i = mt*16 + lk*4 + r; if (i > 97) i = 97;
    int ibase = i*98;
    #pragma unroll
    for (int nt = 0; nt < 7; nt++){
      int j = nt*16 + l16;
      float add = (j < 98) ? (bh[ibase + j] + mm[ibase + j]) : -1e30f;
      float val = s[nt][r] + add;
      s[nt][r] = val;
      mx[r] = fmaxf(mx[r], val);
    }
  }
  #pragma unroll
  for (int r = 0; r < 4; r++){
    #pragma unroll
    for (int off = 1; off < 16; off <<= 1) mx[r] = fmaxf(mx[r], __shfl_xor(mx[r], off));
  }
  float sm[4] = {0.f,0.f,0.f,0.f};
  #pragma unroll
  for (int r = 0; r < 4; r++){
    #pragma unroll
    for (int nt = 0; nt < 7; nt++){
      float e = __expf(s[nt][r] - mx[r]);
      s[nt][r] = e; sm[r] += e;
    }
  }
  #pragma unroll
  for (int r = 0; r < 4; r++){
    #pragma unroll
    for (int off = 1; off < 16; off <<= 1) sm[r] += __shfl_xor(sm[r], off);
    sm[r] = 1.f / sm[r];
  }

  unsigned short* Pw = &P[wid][0];
  { int rr = lane >> 2, cc = 112 + (lane & 3)*4;
    *(uint2*)&Pw[rr*136 + cc] = make_uint2(0u, 0u); }   // zero pad cols 112..127
  #pragma unroll
  for (int r = 0; r < 4; r++)
    #pragma unroll
    for (int nt = 0; nt < 7; nt++)
      Pw[(lk*4 + r)*136 + nt*16 + l16] = f2bf(s[nt][r]*sm[r]);
  __syncthreads();

  f32x4 o0 = (f32x4){0.f,0.f,0.f,0.f}, o1 = (f32x4){0.f,0.f,0.f,0.f};
  #pragma unroll
  for (int kcc = 0; kcc < 4; kcc++){
    bf16x8 pa = *(const bf16x8*)&Pw[l16*136 + kcc*32 + lk*8];
    bf16x8 v0, v1;
    #pragma unroll
    for (int j = 0; j < 8; j++){
      int k = kcc*32 + lk*8 + j; if (k > 97) k = 97;   // P is zero there anyway
      v0[j] = (short)vb[k*32 + l16];
      v1[j] = (short)vb[k*32 + 16 + l16];
    }
    o0 = __builtin_amdgcn_mfma_f32_16x16x32_bf16(pa, v0, o0, 0, 0, 0);
    o1 = __builtin_amdgcn_mfma_f32_16x16x32_bf16(pa, v1, o1, 0, 0, 0);
  }
  #pragma unroll
  for (int r = 0; r < 4; r++){
    int n = mt*16 + lk*4 + r;
    if (n < 98){
      size_t ob = ((size_t)w*98 + n)*256 + h*32;
      obuf[ob + l16]      = f2bf(o0[r]);
      obuf[ob + 16 + l16] = f2bf(o1[r]);
    }
  }
}

extern "C" void kernel_launch(void* const* d_in, const int* in_sizes, int n_in,
                              void* d_out, int out_size, void* d_ws, size_t ws_size,
                              hipStream_t stream)
{
  const float* x     = (const float*)d_in[0];
  const float* maskm = (const float*)d_in[1];
  const int*   ri    = (const int*)d_in[2];
  const float* tbl   = (const float*)d_in[3];
  const float* n1w   = (const float*)d_in[4];
  const float* n1b   = (const float*)d_in[5];
  const float* qkvw  = (const float*)d_in[6];
  const float* qkvbv = (const float*)d_in[7];
  const float* projw = (const float*)d_in[8];
  const float* projb = (const float*)d_in[9];
  const float* n2w   = (const float*)d_in[10];
  const float* n2b   = (const float*)d_in[11];
  const float* fc1w  = (const float*)d_in[12];
  const float* fc1b  = (const float*)d_in[13];
  const float* fc2w  = (const float*)d_in[14];
  const float* fc2b  = (const float*)d_in[15];
  float* dout = (float*)d_out;
  char* ws = (char*)d_ws;

  // workspace layout (bytes); peak need ~207.6 MB
  unsigned short* wq = (unsigned short*)(ws + 0);         // 768*256 bf16
  unsigned short* wp = (unsigned short*)(ws + 393216);    // 256*256 bf16
  unsigned short* w1 = (unsigned short*)(ws + 524288);    // 1024*256 bf16
  unsigned short* w2 = (unsigned short*)(ws + 1048576);   // 256*1024 bf16
  float* biasf       = (float*)(ws + 1572864);            // 8*9604 f32
  unsigned short* hb   = (unsigned short*)(ws + 2097152);   // 100352*256 bf16 (later: attn out)
  unsigned short* qkvB = (unsigned short*)(ws + 53477376);  // 3*100352*256 bf16 (later: h2, g)
  unsigned short* ob = hb;
  unsigned short* h2 = qkvB;
  unsigned short* g  = (unsigned short*)(ws + 53477376 + 51380224);

  cvtk<<<768, 256, 0, stream>>>(qkvw, wq, 196608);
  cvtk<<<256, 256, 0, stream>>>(projw, wp, 65536);
  cvtk<<<1024, 256, 0, stream>>>(fc1w, w1, 262144);
  cvtk<<<1024, 256, 0, stream>>>(fc2w, w2, 262144);
  biask<<<(76832 + 255)/256, 256, 0, stream>>>(ri, tbl, biasf);

  lnk<<<25088, 256, 0, stream>>>(x, n1w, n1b, hb, 0);                       // LN1+shift+window
  gemmk<0><<<784*6, 256, 0, stream>>>(hb, wq, qkvbv, 256, 6, qkvB, nullptr, nullptr, 0);   // qkv
  attnk<<<14336, 256, 0, stream>>>(qkvB, biasf, maskm, ob);                 // attention
  gemmk<1><<<784*2, 256, 0, stream>>>(ob, wp, projb, 256, 2, nullptr, x, dout, 0);         // proj+residual
  lnk<<<25088, 256, 0, stream>>>(dout, n2w, n2b, h2, 1);                    // LN2
  for (int c = 0; c < 4; c++){
    gemmk<2><<<196*8, 256, 0, stream>>>(h2 + (size_t)c*25088*256, w1, fc1b, 256, 8, g, nullptr, nullptr, 0);
    gemmk<3><<<196*2, 256, 0, stream>>>(g, w2, fc2b, 1024, 2, nullptr, nullptr, dout, c*25088);
  }
}